// Round 12
// baseline (44.078 us; speedup 1.0000x reference)
//
#include <hip/hip_runtime.h>
#include <stdint.h>

// DeLaN forward, D=2, H1=64. R12 = R11 (proven 27.7us, absmax 0.0078125)
//  + p0w/p1w (f16 packs of W1, tile-invariant) hoisted out of the t-loop
//  + b1a in registers (kills 4 b128 LDS reads/tile)
//  + next-tile x prefetch (loads issued before the long compute body)
// All computed values bit-identical to R11.

typedef __attribute__((ext_vector_type(8))) _Float16 f16x8;
typedef __attribute__((ext_vector_type(4))) float f32x4;
typedef __attribute__((ext_vector_type(2))) float f32x2;
typedef __attribute__((ext_vector_type(4))) unsigned int u32x4;
typedef __attribute__((ext_vector_type(2))) unsigned int u32x2;

#define MFMA16(A,B,C) __builtin_amdgcn_mfma_f32_16x16x32_f16((A),(B),(C),0,0,0)

static __device__ __forceinline__ f32x2 pk_fma(f32x2 a, f32x2 b, f32x2 c) {
    f32x2 d;
    asm("v_pk_fma_f32 %0, %1, %2, %3" : "=v"(d) : "v"(a), "v"(b), "v"(c));
    return d;
}
static __device__ __forceinline__ f32x2 pk_mul(f32x2 a, f32x2 b) {
    f32x2 d;
    asm("v_pk_mul_f32 %0, %1, %2" : "=v"(d) : "v"(a), "v"(b));
    return d;
}
static __device__ __forceinline__ unsigned pkmul16(unsigned a, unsigned b) {
    unsigned d;
    asm("v_pk_mul_f16 %0, %1, %2" : "=v"(d) : "v"(a), "v"(b));
    return d;
}
// sum over lanes {l, l^16, l^32, l^48} (result in every lane), pure VALU
static __device__ __forceinline__ float qsum(float v) {
    float a = v, b = v;
    asm("v_permlane16_swap_b32 %0, %1" : "+v"(a), "+v"(b));
    const float s = a + b;
    float c = s, d = s;
    asm("v_permlane32_swap_b32 %0, %1" : "+v"(c), "+v"(d));
    return c + d;
}
// fetch v from partner lane l^16 (R10/R11-proven)
static __device__ __forceinline__ float partner16(float v) {
    float a = v, b = v;
    asm("v_permlane16_swap_b32 %0, %1" : "+v"(a), "+v"(b));
    return (a + b) - v;
}
static __device__ __forceinline__ f16x8 mk_f16x8(float4 a, float4 b) {
    f16x8 f;
    f[0] = (_Float16)a.x; f[1] = (_Float16)a.y;
    f[2] = (_Float16)a.z; f[3] = (_Float16)a.w;
    f[4] = (_Float16)b.x; f[5] = (_Float16)b.y;
    f[6] = (_Float16)b.z; f[7] = (_Float16)b.w;
    return f;
}

__global__ __launch_bounds__(256, 3) void delan_fwd(
    const float* __restrict__ x,
    const float* __restrict__ W1,  const float* __restrict__ b1,
    const float* __restrict__ W1a, const float* __restrict__ b1a,
    const float* __restrict__ W2,  const float* __restrict__ b2,
    const float* __restrict__ W3,  const float* __restrict__ b3,
    const float* __restrict__ W4,  const float* __restrict__ b4,
    float* __restrict__ out, int n_total)
{
    // union pool: afrag [2][4][2][64][8] f16 (16384B) overlaid by
    // scr [4][3][576] u32 (27648B). afrag dead after register hoist.
    __shared__ __align__(16) unsigned char upool[27648];
    __shared__ float w0s[64], w1s[64], bs[64];   // W1 SoA + b1 (Phase A)
    __shared__ float w3s[2][64];                 // W3 rows (l-dots)

    _Float16 (*afr)[4][2][64][8] = (_Float16 (*)[4][2][64][8])upool;
    unsigned (*scr)[3][576]      = (unsigned (*)[3][576])upool;

    const int tid  = threadIdx.x;
    const int lane = tid & 63;
    const int wid  = tid >> 6;
    const int p    = lane & 15;
    const int qrt  = lane >> 4;

    // ---- Per-block constant build (R11-identical patterns) ----
    if (tid < 64) {
        const int k = tid;
        w0s[k] = W1[2*k]; w1s[k] = W1[2*k+1]; bs[k] = b1[k];
        w3s[0][k] = W3[k]; w3s[1][k] = W3[64 + k];
    }
    {
        const int ht = wid;                 // wave wid builds h-tile wid
#pragma unroll
        for (int kh = 0; kh < 2; ++kh) {
            const int row = ht * 16 + p;
            const int kb  = kh * 32 + qrt * 8;
            float wv[8];
            *(float4*)&wv[0] = *(const float4*)(W1a + row * 64 + kb);
            *(float4*)&wv[4] = *(const float4*)(W1a + row * 64 + kb + 4);
            f16x8 hi, lo;
#pragma unroll
            for (int j = 0; j < 8; ++j) {
                const _Float16 h = (_Float16)wv[j];
                hi[j] = h;
                lo[j] = (_Float16)((wv[j] - (float)h) * 4096.0f);
            }
            *(f16x8*)&afr[0][ht][kh][lane][0] = hi;
            *(f16x8*)&afr[1][ht][kh][lane][0] = lo;
        }
    }

    // b1a in registers (R10-proven pattern)
    f32x4 b1a_r[4];
#pragma unroll
    for (int ht = 0; ht < 4; ++ht)
        b1a_r[ht] = *(const f32x4*)(b1a + ht * 16 + qrt * 4);

    // Stage-2 constant A frags: rows 0:W2c0 1:W2c1 2:W4 3:W3c0 4:W3c1, rest 0
    f16x8 A2[2];
    {
        const float* arow = (p == 0) ? W2 : (p == 1) ? (W2 + 64)
                          : (p == 2) ? W4 : (p == 3) ? W3 : (W3 + 64);
#pragma unroll
        for (int kh = 0; kh < 2; ++kh) {
            const int kb = kh * 32 + qrt * 8;
            f16x8 f = mk_f16x8(*(const float4*)(arow + kb),
                               *(const float4*)(arow + kb + 4));
            if (p >= 5) {
#pragma unroll
                for (int j = 0; j < 8; ++j) f[j] = (_Float16)0.0f;
            }
            A2[kh] = f;
        }
    }
    __syncthreads();

    // ---- Hoist stage-1 A fragments (hi+lo) into registers, free LDS ----
    f16x8 Ahr[4][2], Alr[4][2];
#pragma unroll
    for (int ht = 0; ht < 4; ++ht) {
#pragma unroll
        for (int kh = 0; kh < 2; ++kh) {
            Ahr[ht][kh] = *(const f16x8*)&afr[0][ht][kh][lane][0];
            Alr[ht][kh] = *(const f16x8*)&afr[1][ht][kh][lane][0];
        }
    }
    __syncthreads();   // protect scr overlay of afrag region

    // ---- Tile-invariant Phase-A weight packs (hoisted out of t-loop) ----
    unsigned p0w_r[2][4], p1w_r[2][4];
#pragma unroll
    for (int kh = 0; kh < 2; ++kh) {
        const int kb = kh * 32 + qrt * 8;
#pragma unroll
        for (int c = 0; c < 4; ++c) {
            const f32x2 w0p = *(const f32x2*)&w0s[kb + 2*c];
            const f32x2 w1p = *(const f32x2*)&w1s[kb + 2*c];
            p0w_r[kh][c] = __builtin_bit_cast(unsigned,
                __builtin_amdgcn_cvt_pkrtz(w0p.x, w0p.y));
            p1w_r[kh][c] = __builtin_bit_cast(unsigned,
                __builtin_amdgcn_cvt_pkrtz(w1p.x, w1p.y));
        }
    }

    const f32x2 c4096  = {4096.0f, 4096.0f};
    const f32x2 cm4096 = {-4096.0f, -4096.0f};
    const long long N  = n_total;

    // ---- x prefetch for tile 0 ----
    int s0 = (blockIdx.x * 4 + 0) * 64 + wid * 16 + p;
    int sc0 = (s0 < n_total) ? s0 : (n_total - 1);
    float2 xa = *(const float2*)(x + 6 * sc0);
    float2 xb = *(const float2*)(x + 6 * sc0 + 2);
    float2 xc = *(const float2*)(x + 6 * sc0 + 4);

#pragma unroll 1
    for (int t = 0; t < 4; ++t) {
        const int s = (blockIdx.x * 4 + t) * 64 + wid * 16 + p;
        const float x0 = xa.x, x1 = xa.y;
        const float x2 = xb.x, x3 = xb.y;
        const float x4 = xc.x, x5 = xc.y;

        // issue next tile's x loads NOW (latency hides under this body)
        if (t < 3) {
            const int sn  = s + 64;
            const int scn = (sn < n_total) ? sn : (n_total - 1);
            xa = *(const float2*)(x + 6 * scn);
            xb = *(const float2*)(x + 6 * scn + 2);
            xc = *(const float2*)(x + 6 * scn + 4);
        }

        // ---- Phase A: B-fragments from LDS weights (R11 verbatim, minus
        //      the hoisted weight cvts) ----
        const f32x2 q00 = {x0, x0};
        const f32x2 q11 = {x1, x1};
        u32x4 Bhh[2], Bhl[2], Bu0[2], Bu1[2];
#pragma unroll
        for (int kh = 0; kh < 2; ++kh) {
            const int kb = kh * 32 + qrt * 8;
#pragma unroll
            for (int c = 0; c < 4; ++c) {
                const f32x2 w0p = *(const f32x2*)&w0s[kb + 2*c];
                const f32x2 w1p = *(const f32x2*)&w1s[kb + 2*c];
                const f32x2 bp  = *(const f32x2*)&bs [kb + 2*c];
                const f32x2 prep = pk_fma(w0p, q00, pk_fma(w1p, q11, bp));
                const bool pos0 = prep.x > 0.0f;
                const bool pos1 = prep.y > 0.0f;
                const unsigned mlo = pos0 ? 0x00003C00u : 0x0000A11Fu;
                const unsigned mhi = pos1 ? 0x3C000000u : 0xA11F0000u;
                const unsigned drw = mlo | mhi;
                Bu0[kh][c] = pkmul16(p0w_r[kh][c], drw);
                Bu1[kh][c] = pkmul16(p1w_r[kh][c], drw);
                f32x2 sp;
                sp.x = pos0 ? 1.0f : 0.01f;
                sp.y = pos1 ? 1.0f : 0.01f;
                const f32x2 h1p = pk_mul(prep, sp);
                const auto hhv = __builtin_amdgcn_cvt_pkrtz(h1p.x, h1p.y);
                Bhh[kh][c] = __builtin_bit_cast(unsigned, hhv);
                f32x2 hf;
                hf.x = (float)hhv[0];
                hf.y = (float)hhv[1];
                const f32x2 tt = pk_mul(h1p, c4096);
                const f32x2 rp = pk_fma(hf, cm4096, tt);   // (h1 - hh) * 4096
                Bhl[kh][c] = __builtin_bit_cast(unsigned,
                    __builtin_amdgcn_cvt_pkrtz(rp.x, rp.y));
            }
        }

        // ---- Phase B: stage-1 MFMAs (A from regs) + minimal epilogue ----
        float al0 = 0.f, al1 = 0.f;
#pragma unroll
        for (int ht = 0; ht < 4; ++ht) {
            const f16x8 Ah0 = Ahr[ht][0];
            const f16x8 Ah1 = Ahr[ht][1];
            const f16x8 Al0 = Alr[ht][0];
            const f16x8 Al1 = Alr[ht][1];
            const f16x8 bh0 = __builtin_bit_cast(f16x8, Bhh[0]);
            const f16x8 bh1 = __builtin_bit_cast(f16x8, Bhh[1]);
            const f16x8 bl0 = __builtin_bit_cast(f16x8, Bhl[0]);
            const f16x8 bl1 = __builtin_bit_cast(f16x8, Bhl[1]);
            const f16x8 bu00 = __builtin_bit_cast(f16x8, Bu0[0]);
            const f16x8 bu01 = __builtin_bit_cast(f16x8, Bu0[1]);
            const f16x8 bu10 = __builtin_bit_cast(f16x8, Bu1[0]);
            const f16x8 bu11 = __builtin_bit_cast(f16x8, Bu1[1]);

            f32x4 Chi = b1a_r[ht];
            f32x4 Clo = {0.f,0.f,0.f,0.f};
            f32x4 Cz0 = {0.f,0.f,0.f,0.f};
            f32x4 Cz1 = {0.f,0.f,0.f,0.f};
            Chi = MFMA16(Ah0, bh0, Chi);  Chi = MFMA16(Ah1, bh1, Chi);
            Clo = MFMA16(Ah0, bl0, Clo);  Clo = MFMA16(Ah1, bl1, Clo);
            Clo = MFMA16(Al0, bh0, Clo);  Clo = MFMA16(Al1, bh1, Clo);
            Cz0 = MFMA16(Ah0, bu00, Cz0); Cz0 = MFMA16(Ah1, bu01, Cz0);
            Cz1 = MFMA16(Ah0, bu10, Cz1); Cz1 = MFMA16(Ah1, bu11, Cz1);

            const f32x4 w3a = *(const f32x4*)&w3s[0][ht * 16 + qrt * 4];
            const f32x4 w3b = *(const f32x4*)&w3s[1][ht * 16 + qrt * 4];
            float h2v[4], d0v[4], d1v[4];
#pragma unroll
            for (int r = 0; r < 4; ++r) {
                const float ah = fmaf(2.44140625e-4f, Clo[r], Chi[r]);
                const bool pos = ah > 0.0f;
                const float h2 = pos ? ah : 0.01f * ah;
                h2v[r] = h2;
                al0 = fmaf(w3a[r], h2, al0);
                al1 = fmaf(w3b[r], h2, al1);
                d0v[r] = pos ? Cz0[r] : -0.01f * Cz0[r];
                d1v[r] = pos ? Cz1[r] : -0.01f * Cz1[r];
            }
            u32x2 ph, pd0, pd1;
            ph[0]  = __builtin_bit_cast(unsigned, __builtin_amdgcn_cvt_pkrtz(h2v[0], h2v[1]));
            ph[1]  = __builtin_bit_cast(unsigned, __builtin_amdgcn_cvt_pkrtz(h2v[2], h2v[3]));
            pd0[0] = __builtin_bit_cast(unsigned, __builtin_amdgcn_cvt_pkrtz(d0v[0], d0v[1]));
            pd0[1] = __builtin_bit_cast(unsigned, __builtin_amdgcn_cvt_pkrtz(d0v[2], d0v[3]));
            pd1[0] = __builtin_bit_cast(unsigned, __builtin_amdgcn_cvt_pkrtz(d1v[0], d1v[1]));
            pd1[1] = __builtin_bit_cast(unsigned, __builtin_amdgcn_cvt_pkrtz(d1v[2], d1v[3]));
            const int iw = p * 36 + 8 * ht + 2 * qrt;
            *(u32x2*)&scr[wid][0][iw] = ph;
            *(u32x2*)&scr[wid][1][iw] = pd0;
            *(u32x2*)&scr[wid][2][iw] = pd1;
        }

        // ---- Stage-2 MFMAs: g0,g1,oo from h2; p/r dots from d0,d1 ----
        const int ir = p * 36 + 4 * qrt;
        const f16x8 Bh2a = *(const f16x8*)&scr[wid][0][ir];
        const f16x8 Bh2b = *(const f16x8*)&scr[wid][0][ir + 16];
        const f16x8 Bd0a = *(const f16x8*)&scr[wid][1][ir];
        const f16x8 Bd0b = *(const f16x8*)&scr[wid][1][ir + 16];
        const f16x8 Bd1a = *(const f16x8*)&scr[wid][2][ir];
        const f16x8 Bd1b = *(const f16x8*)&scr[wid][2][ir + 16];
        f32x4 Ch  = {0.f,0.f,0.f,0.f};
        f32x4 Cd0 = {0.f,0.f,0.f,0.f};
        f32x4 Cd1 = {0.f,0.f,0.f,0.f};
        Ch  = MFMA16(A2[0], Bh2a, Ch);   Ch  = MFMA16(A2[1], Bh2b, Ch);
        Cd0 = MFMA16(A2[0], Bd0a, Cd0);  Cd0 = MFMA16(A2[1], Bd0b, Cd0);
        Cd1 = MFMA16(A2[0], Bd1a, Cd1);  Cd1 = MFMA16(A2[1], Bd1b, Cd1);

        // valid on qrt==0 lanes (C rows 0..3); row 4 via partner16
        const float g0 = Ch[0] + b2[0];
        const float g1 = Ch[1] + b2[1];
        const float oo = Ch[2] + b4[0];
        const float r0 = Cd0[2], p00 = Cd0[3];
        const float r1 = Cd1[2], p01 = Cd1[3];
        const float p10 = partner16(Cd0[0]);
        const float p11 = partner16(Cd1[0]);
        const float l0 = qsum(al0) + b3[0];
        const float l1 = qsum(al1) + b3[1];

        // ---- Tail: 2x2 algebra (R1-identical; valid on qrt==0) ----
        const float ld0 = fmaxf(l0, 0.0f);
        const float ld1 = fmaxf(l1, 0.0f);
        const float dr30 = (l0 > 0.0f) ? 1.0f : 0.0f;
        const float dr31 = (l1 > 0.0f) ? 1.0f : 0.0f;

        const float da00 = dr30 * p00, da01 = dr30 * p01;
        const float da10 = dr31 * p10, da11 = dr31 * p11;

        const float l00 = ld0, l10 = oo, l11 = ld1;

        const float m00 = da00 * x2 + da01 * x3;
        const float m11 = da10 * x2 + da11 * x3;
        const float m10 = r0  * x2 + r1  * x3;

        const float eps = 1e-5f;
        const float Hm00 = fmaf(l00, l00, eps);
        const float Hm01 = l00 * l10;
        const float Hm11 = fmaf(l10, l10, fmaf(l11, l11, eps));

        const float dH00 = 2.0f * l00 * m00;
        const float dH01 = fmaf(l00, m10, l10 * m00);
        const float dH11 = 2.0f * fmaf(l10, m10, l11 * m11);

        const float x22 = x2 * x2, x23 = x2 * x3, x33 = x3 * x3;
        const float quad0 = 2.0f * (da00 * l00 * x22
                          + (fmaf(da00, l10, r0 * l00)) * x23
                          + (fmaf(r0, l10, da10 * l11)) * x33);
        const float quad1 = 2.0f * (da01 * l00 * x22
                          + (fmaf(da01, l10, r1 * l00)) * x23
                          + (fmaf(r1, l10, da11 * l11)) * x33);

        const float c0 = fmaf(dH00, x2, dH01 * x3) - 0.5f * quad0;
        const float c1 = fmaf(dH01, x2, dH11 * x3) - 0.5f * quad1;

        const float tau0 = fmaf(Hm00, x4, Hm01 * x5) + c0 + g0;
        const float tau1 = fmaf(Hm01, x4, Hm11 * x5) + c1 + g1;

        if (s < n_total && qrt == 0) {
            *((float2*)out + s)           = make_float2(tau0, tau1);
            *((float4*)(out + 2 * N) + s) = make_float4(Hm00, Hm01, Hm01, Hm11);
            *((float2*)(out + 6 * N) + s) = make_float2(c0, c1);
            *((float2*)(out + 8 * N) + s) = make_float2(g0, g1);
        }
    }
}

extern "C" void kernel_launch(void* const* d_in, const int* in_sizes, int n_in,
                              void* d_out, int out_size, void* d_ws, size_t ws_size,
                              hipStream_t stream) {
    const float* x   = (const float*)d_in[0];
    const float* W1  = (const float*)d_in[1];
    const float* b1  = (const float*)d_in[2];
    const float* W1a = (const float*)d_in[3];
    const float* b1a = (const float*)d_in[4];
    const float* W2  = (const float*)d_in[5];
    const float* b2  = (const float*)d_in[6];
    const float* W3  = (const float*)d_in[7];
    const float* b3  = (const float*)d_in[8];
    const float* W4  = (const float*)d_in[9];
    const float* b4  = (const float*)d_in[10];
    float* out = (float*)d_out;

    const int n_total = in_sizes[0] / 6;
    const int block = 256;
    const int grid = (n_total + 255) / 256;   // 256 samples/block (4 tiles x 64)
    delan_fwd<<<grid, block, 0, stream>>>(x, W1, b1, W1a, b1a, W2, b2,
                                          W3, b3, W4, b4, out, n_total);
}

// Round 13
// 27.652 us; speedup vs baseline: 1.5940x; 1.5940x over previous
//
#include <hip/hip_runtime.h>
#include <stdint.h>

// DeLaN forward, D=2, H1=64. R13 = R11 VERBATIM REVERT (proven 27.7us,
// absmax 0.0078125). R12's register hoists (p0w/b1a/prefetch) pushed the
// allocator past the spill cliff (VGPR 84, scratch traffic: WRITE 43MB) —
// reverted. R11 sits just under the register budget at 3 waves/EU:
//  - stage-1 A-frags (hi+lo) hoisted LDS->registers once per block
//  - LDS union: stage-2 scratch overlays dead afrag region (2nd barrier)
//  - full stage-2 MFMA for g0,g1,oo,p00,p10,p11,r0,r1 (partner16)
//  - sign-critical l0,l1 fp32 fma+qsum; Phase A packed-VALU hi/lo split

typedef __attribute__((ext_vector_type(8))) _Float16 f16x8;
typedef __attribute__((ext_vector_type(4))) float f32x4;
typedef __attribute__((ext_vector_type(2))) float f32x2;
typedef __attribute__((ext_vector_type(4))) unsigned int u32x4;
typedef __attribute__((ext_vector_type(2))) unsigned int u32x2;

#define MFMA16(A,B,C) __builtin_amdgcn_mfma_f32_16x16x32_f16((A),(B),(C),0,0,0)

static __device__ __forceinline__ f32x2 pk_fma(f32x2 a, f32x2 b, f32x2 c) {
    f32x2 d;
    asm("v_pk_fma_f32 %0, %1, %2, %3" : "=v"(d) : "v"(a), "v"(b), "v"(c));
    return d;
}
static __device__ __forceinline__ f32x2 pk_mul(f32x2 a, f32x2 b) {
    f32x2 d;
    asm("v_pk_mul_f32 %0, %1, %2" : "=v"(d) : "v"(a), "v"(b));
    return d;
}
static __device__ __forceinline__ unsigned pkmul16(unsigned a, unsigned b) {
    unsigned d;
    asm("v_pk_mul_f16 %0, %1, %2" : "=v"(d) : "v"(a), "v"(b));
    return d;
}
// sum over lanes {l, l^16, l^32, l^48} (result in every lane), pure VALU
static __device__ __forceinline__ float qsum(float v) {
    float a = v, b = v;
    asm("v_permlane16_swap_b32 %0, %1" : "+v"(a), "+v"(b));
    const float s = a + b;
    float c = s, d = s;
    asm("v_permlane32_swap_b32 %0, %1" : "+v"(c), "+v"(d));
    return c + d;
}
// fetch v from partner lane l^16 (R10-proven)
static __device__ __forceinline__ float partner16(float v) {
    float a = v, b = v;
    asm("v_permlane16_swap_b32 %0, %1" : "+v"(a), "+v"(b));
    return (a + b) - v;
}
static __device__ __forceinline__ f16x8 mk_f16x8(float4 a, float4 b) {
    f16x8 f;
    f[0] = (_Float16)a.x; f[1] = (_Float16)a.y;
    f[2] = (_Float16)a.z; f[3] = (_Float16)a.w;
    f[4] = (_Float16)b.x; f[5] = (_Float16)b.y;
    f[6] = (_Float16)b.z; f[7] = (_Float16)b.w;
    return f;
}

__global__ __launch_bounds__(256, 3) void delan_fwd(
    const float* __restrict__ x,
    const float* __restrict__ W1,  const float* __restrict__ b1,
    const float* __restrict__ W1a, const float* __restrict__ b1a,
    const float* __restrict__ W2,  const float* __restrict__ b2,
    const float* __restrict__ W3,  const float* __restrict__ b3,
    const float* __restrict__ W4,  const float* __restrict__ b4,
    float* __restrict__ out, int n_total)
{
    // union pool: afrag [2][4][2][64][8] f16 (16384B) overlaid by
    // scr [4][3][576] u32 (27648B). afrag dead after register hoist.
    __shared__ __align__(16) unsigned char upool[27648];
    __shared__ float w0s[64], w1s[64], bs[64];   // W1 SoA + b1 (Phase A)
    __shared__ float w3s[2][64];                 // W3 rows (l-dots)
    __shared__ float bls[64];                    // b1a

    _Float16 (*afr)[4][2][64][8] = (_Float16 (*)[4][2][64][8])upool;
    unsigned (*scr)[3][576]      = (unsigned (*)[3][576])upool;

    const int tid  = threadIdx.x;
    const int lane = tid & 63;
    const int wid  = tid >> 6;
    const int p    = lane & 15;
    const int qrt  = lane >> 4;

    // ---- Per-block constant build (R9-identical patterns) ----
    if (tid < 64) {
        const int k = tid;
        w0s[k] = W1[2*k]; w1s[k] = W1[2*k+1]; bs[k] = b1[k];
        w3s[0][k] = W3[k]; w3s[1][k] = W3[64 + k];
        bls[k] = b1a[k];
    }
    {
        const int ht = wid;                 // wave wid builds h-tile wid
#pragma unroll
        for (int kh = 0; kh < 2; ++kh) {
            const int row = ht * 16 + p;
            const int kb  = kh * 32 + qrt * 8;
            float wv[8];
            *(float4*)&wv[0] = *(const float4*)(W1a + row * 64 + kb);
            *(float4*)&wv[4] = *(const float4*)(W1a + row * 64 + kb + 4);
            f16x8 hi, lo;
#pragma unroll
            for (int j = 0; j < 8; ++j) {
                const _Float16 h = (_Float16)wv[j];
                hi[j] = h;
                lo[j] = (_Float16)((wv[j] - (float)h) * 4096.0f);
            }
            *(f16x8*)&afr[0][ht][kh][lane][0] = hi;
            *(f16x8*)&afr[1][ht][kh][lane][0] = lo;
        }
    }

    // Stage-2 constant A frags: rows 0:W2c0 1:W2c1 2:W4 3:W3c0 4:W3c1, rest 0
    f16x8 A2[2];
    {
        const float* arow = (p == 0) ? W2 : (p == 1) ? (W2 + 64)
                          : (p == 2) ? W4 : (p == 3) ? W3 : (W3 + 64);
#pragma unroll
        for (int kh = 0; kh < 2; ++kh) {
            const int kb = kh * 32 + qrt * 8;
            f16x8 f = mk_f16x8(*(const float4*)(arow + kb),
                               *(const float4*)(arow + kb + 4));
            if (p >= 5) {
#pragma unroll
                for (int j = 0; j < 8; ++j) f[j] = (_Float16)0.0f;
            }
            A2[kh] = f;
        }
    }
    __syncthreads();

    // ---- Hoist stage-1 A fragments (hi+lo) into registers, then free LDS ----
    f16x8 Ahr[4][2], Alr[4][2];
#pragma unroll
    for (int ht = 0; ht < 4; ++ht) {
#pragma unroll
        for (int kh = 0; kh < 2; ++kh) {
            Ahr[ht][kh] = *(const f16x8*)&afr[0][ht][kh][lane][0];
            Alr[ht][kh] = *(const f16x8*)&afr[1][ht][kh][lane][0];
        }
    }
    __syncthreads();   // protect scr overlay of afrag region

    const f32x2 c4096  = {4096.0f, 4096.0f};
    const f32x2 cm4096 = {-4096.0f, -4096.0f};
    const long long N  = n_total;

#pragma unroll 1
    for (int t = 0; t < 4; ++t) {
        const int s  = (blockIdx.x * 4 + t) * 64 + wid * 16 + p;
        const int sc = (s < n_total) ? s : (n_total - 1);

        const float2 xa = *(const float2*)(x + 6 * sc);
        const float2 xb = *(const float2*)(x + 6 * sc + 2);
        const float2 xc = *(const float2*)(x + 6 * sc + 4);
        const float x0 = xa.x, x1 = xa.y;
        const float x2 = xb.x, x3 = xb.y;
        const float x4 = xc.x, x5 = xc.y;

        // ---- Phase A: B-fragments from LDS weights (R9 verbatim) ----
        const f32x2 q00 = {x0, x0};
        const f32x2 q11 = {x1, x1};
        u32x4 Bhh[2], Bhl[2], Bu0[2], Bu1[2];
#pragma unroll
        for (int kh = 0; kh < 2; ++kh) {
            const int kb = kh * 32 + qrt * 8;
#pragma unroll
            for (int c = 0; c < 4; ++c) {
                const f32x2 w0p = *(const f32x2*)&w0s[kb + 2*c];
                const f32x2 w1p = *(const f32x2*)&w1s[kb + 2*c];
                const f32x2 bp  = *(const f32x2*)&bs [kb + 2*c];
                const f32x2 prep = pk_fma(w0p, q00, pk_fma(w1p, q11, bp));
                const bool pos0 = prep.x > 0.0f;
                const bool pos1 = prep.y > 0.0f;
                const unsigned mlo = pos0 ? 0x00003C00u : 0x0000A11Fu;
                const unsigned mhi = pos1 ? 0x3C000000u : 0xA11F0000u;
                const unsigned drw = mlo | mhi;
                const unsigned p0w = __builtin_bit_cast(unsigned,
                    __builtin_amdgcn_cvt_pkrtz(w0p.x, w0p.y));
                const unsigned p1w = __builtin_bit_cast(unsigned,
                    __builtin_amdgcn_cvt_pkrtz(w1p.x, w1p.y));
                Bu0[kh][c] = pkmul16(p0w, drw);
                Bu1[kh][c] = pkmul16(p1w, drw);
                f32x2 sp;
                sp.x = pos0 ? 1.0f : 0.01f;
                sp.y = pos1 ? 1.0f : 0.01f;
                const f32x2 h1p = pk_mul(prep, sp);
                const auto hhv = __builtin_amdgcn_cvt_pkrtz(h1p.x, h1p.y);
                Bhh[kh][c] = __builtin_bit_cast(unsigned, hhv);
                f32x2 hf;
                hf.x = (float)hhv[0];
                hf.y = (float)hhv[1];
                const f32x2 tt = pk_mul(h1p, c4096);
                const f32x2 rp = pk_fma(hf, cm4096, tt);   // (h1 - hh) * 4096
                Bhl[kh][c] = __builtin_bit_cast(unsigned,
                    __builtin_amdgcn_cvt_pkrtz(rp.x, rp.y));
            }
        }

        // ---- Phase B: stage-1 MFMAs (A from regs) + minimal epilogue ----
        float al0 = 0.f, al1 = 0.f;
#pragma unroll
        for (int ht = 0; ht < 4; ++ht) {
            const f16x8 Ah0 = Ahr[ht][0];
            const f16x8 Ah1 = Ahr[ht][1];
            const f16x8 Al0 = Alr[ht][0];
            const f16x8 Al1 = Alr[ht][1];
            const f16x8 bh0 = __builtin_bit_cast(f16x8, Bhh[0]);
            const f16x8 bh1 = __builtin_bit_cast(f16x8, Bhh[1]);
            const f16x8 bl0 = __builtin_bit_cast(f16x8, Bhl[0]);
            const f16x8 bl1 = __builtin_bit_cast(f16x8, Bhl[1]);
            const f16x8 bu00 = __builtin_bit_cast(f16x8, Bu0[0]);
            const f16x8 bu01 = __builtin_bit_cast(f16x8, Bu0[1]);
            const f16x8 bu10 = __builtin_bit_cast(f16x8, Bu1[0]);
            const f16x8 bu11 = __builtin_bit_cast(f16x8, Bu1[1]);

            f32x4 Chi = *(const f32x4*)&bls[ht * 16 + qrt * 4];  // b1a init
            f32x4 Clo = {0.f,0.f,0.f,0.f};
            f32x4 Cz0 = {0.f,0.f,0.f,0.f};
            f32x4 Cz1 = {0.f,0.f,0.f,0.f};
            Chi = MFMA16(Ah0, bh0, Chi);  Chi = MFMA16(Ah1, bh1, Chi);
            Clo = MFMA16(Ah0, bl0, Clo);  Clo = MFMA16(Ah1, bl1, Clo);
            Clo = MFMA16(Al0, bh0, Clo);  Clo = MFMA16(Al1, bh1, Clo);
            Cz0 = MFMA16(Ah0, bu00, Cz0); Cz0 = MFMA16(Ah1, bu01, Cz0);
            Cz1 = MFMA16(Ah0, bu10, Cz1); Cz1 = MFMA16(Ah1, bu11, Cz1);

            const f32x4 w3a = *(const f32x4*)&w3s[0][ht * 16 + qrt * 4];
            const f32x4 w3b = *(const f32x4*)&w3s[1][ht * 16 + qrt * 4];
            float h2v[4], d0v[4], d1v[4];
#pragma unroll
            for (int r = 0; r < 4; ++r) {
                const float ah = fmaf(2.44140625e-4f, Clo[r], Chi[r]);
                const bool pos = ah > 0.0f;
                const float h2 = pos ? ah : 0.01f * ah;
                h2v[r] = h2;
                al0 = fmaf(w3a[r], h2, al0);
                al1 = fmaf(w3b[r], h2, al1);
                d0v[r] = pos ? Cz0[r] : -0.01f * Cz0[r];
                d1v[r] = pos ? Cz1[r] : -0.01f * Cz1[r];
            }
            u32x2 ph, pd0, pd1;
            ph[0]  = __builtin_bit_cast(unsigned, __builtin_amdgcn_cvt_pkrtz(h2v[0], h2v[1]));
            ph[1]  = __builtin_bit_cast(unsigned, __builtin_amdgcn_cvt_pkrtz(h2v[2], h2v[3]));
            pd0[0] = __builtin_bit_cast(unsigned, __builtin_amdgcn_cvt_pkrtz(d0v[0], d0v[1]));
            pd0[1] = __builtin_bit_cast(unsigned, __builtin_amdgcn_cvt_pkrtz(d0v[2], d0v[3]));
            pd1[0] = __builtin_bit_cast(unsigned, __builtin_amdgcn_cvt_pkrtz(d1v[0], d1v[1]));
            pd1[1] = __builtin_bit_cast(unsigned, __builtin_amdgcn_cvt_pkrtz(d1v[2], d1v[3]));
            const int iw = p * 36 + 8 * ht + 2 * qrt;
            *(u32x2*)&scr[wid][0][iw] = ph;
            *(u32x2*)&scr[wid][1][iw] = pd0;
            *(u32x2*)&scr[wid][2][iw] = pd1;
        }

        // ---- Stage-2 MFMAs: g0,g1,oo from h2; p/r dots from d0,d1 ----
        const int ir = p * 36 + 4 * qrt;
        const f16x8 Bh2a = *(const f16x8*)&scr[wid][0][ir];
        const f16x8 Bh2b = *(const f16x8*)&scr[wid][0][ir + 16];
        const f16x8 Bd0a = *(const f16x8*)&scr[wid][1][ir];
        const f16x8 Bd0b = *(const f16x8*)&scr[wid][1][ir + 16];
        const f16x8 Bd1a = *(const f16x8*)&scr[wid][2][ir];
        const f16x8 Bd1b = *(const f16x8*)&scr[wid][2][ir + 16];
        f32x4 Ch  = {0.f,0.f,0.f,0.f};
        f32x4 Cd0 = {0.f,0.f,0.f,0.f};
        f32x4 Cd1 = {0.f,0.f,0.f,0.f};
        Ch  = MFMA16(A2[0], Bh2a, Ch);   Ch  = MFMA16(A2[1], Bh2b, Ch);
        Cd0 = MFMA16(A2[0], Bd0a, Cd0);  Cd0 = MFMA16(A2[1], Bd0b, Cd0);
        Cd1 = MFMA16(A2[0], Bd1a, Cd1);  Cd1 = MFMA16(A2[1], Bd1b, Cd1);

        // valid on qrt==0 lanes (C rows 0..3); row 4 via partner16
        const float g0 = Ch[0] + b2[0];
        const float g1 = Ch[1] + b2[1];
        const float oo = Ch[2] + b4[0];
        const float r0 = Cd0[2], p00 = Cd0[3];
        const float r1 = Cd1[2], p01 = Cd1[3];
        const float p10 = partner16(Cd0[0]);
        const float p11 = partner16(Cd1[0]);
        const float l0 = qsum(al0) + b3[0];
        const float l1 = qsum(al1) + b3[1];

        // ---- Tail: 2x2 algebra (R1-identical; valid on qrt==0) ----
        const float ld0 = fmaxf(l0, 0.0f);
        const float ld1 = fmaxf(l1, 0.0f);
        const float dr30 = (l0 > 0.0f) ? 1.0f : 0.0f;
        const float dr31 = (l1 > 0.0f) ? 1.0f : 0.0f;

        const float da00 = dr30 * p00, da01 = dr30 * p01;
        const float da10 = dr31 * p10, da11 = dr31 * p11;

        const float l00 = ld0, l10 = oo, l11 = ld1;

        const float m00 = da00 * x2 + da01 * x3;
        const float m11 = da10 * x2 + da11 * x3;
        const float m10 = r0  * x2 + r1  * x3;

        const float eps = 1e-5f;
        const float Hm00 = fmaf(l00, l00, eps);
        const float Hm01 = l00 * l10;
        const float Hm11 = fmaf(l10, l10, fmaf(l11, l11, eps));

        const float dH00 = 2.0f * l00 * m00;
        const float dH01 = fmaf(l00, m10, l10 * m00);
        const float dH11 = 2.0f * fmaf(l10, m10, l11 * m11);

        const float x22 = x2 * x2, x23 = x2 * x3, x33 = x3 * x3;
        const float quad0 = 2.0f * (da00 * l00 * x22
                          + (fmaf(da00, l10, r0 * l00)) * x23
                          + (fmaf(r0, l10, da10 * l11)) * x33);
        const float quad1 = 2.0f * (da01 * l00 * x22
                          + (fmaf(da01, l10, r1 * l00)) * x23
                          + (fmaf(r1, l10, da11 * l11)) * x33);

        const float c0 = fmaf(dH00, x2, dH01 * x3) - 0.5f * quad0;
        const float c1 = fmaf(dH01, x2, dH11 * x3) - 0.5f * quad1;

        const float tau0 = fmaf(Hm00, x4, Hm01 * x5) + c0 + g0;
        const float tau1 = fmaf(Hm01, x4, Hm11 * x5) + c1 + g1;

        if (s < n_total && qrt == 0) {
            *((float2*)out + s)           = make_float2(tau0, tau1);
            *((float4*)(out + 2 * N) + s) = make_float4(Hm00, Hm01, Hm01, Hm11);
            *((float2*)(out + 6 * N) + s) = make_float2(c0, c1);
            *((float2*)(out + 8 * N) + s) = make_float2(g0, g1);
        }
    }
}

extern "C" void kernel_launch(void* const* d_in, const int* in_sizes, int n_in,
                              void* d_out, int out_size, void* d_ws, size_t ws_size,
                              hipStream_t stream) {
    const float* x   = (const float*)d_in[0];
    const float* W1  = (const float*)d_in[1];
    const float* b1  = (const float*)d_in[2];
    const float* W1a = (const float*)d_in[3];
    const float* b1a = (const float*)d_in[4];
    const float* W2  = (const float*)d_in[5];
    const float* b2  = (const float*)d_in[6];
    const float* W3  = (const float*)d_in[7];
    const float* b3  = (const float*)d_in[8];
    const float* W4  = (const float*)d_in[9];
    const float* b4  = (const float*)d_in[10];
    float* out = (float*)d_out;

    const int n_total = in_sizes[0] / 6;
    const int block = 256;
    const int grid = (n_total + 255) / 256;   // 256 samples/block (4 tiles x 64)
    delan_fwd<<<grid, block, 0, stream>>>(x, W1, b1, W1a, b1a, W2, b2,
                                          W3, b3, W4, b4, out, n_total);
}